// Round 7
// baseline (427.030 us; speedup 1.0000x reference)
//
#include <hip/hip_runtime.h>
#include <hip/hip_bf16.h>

// Problem constants (FEDformerEncoder): BS=32 CNT=128 W=2048 P=1024 E=8 K=25 L=2
#define BSZ 32
#define CNTS 128
#define WD 2048
#define PD 1024
#define ED 8
#define KSZ 25
#define LN 2
#define MROWS (BSZ*CNTS)   // 4096
#define QKVN (3*PD)        // 3072
#define NWL (PD*WD)        // 2M elements per weight tensor per layer

typedef _Float16 f16;
typedef __attribute__((ext_vector_type(8))) _Float16 f16x8;  // 8 f16 = 4 VGPRs
typedef __attribute__((ext_vector_type(4))) float f32x4;
typedef __attribute__((ext_vector_type(2))) float f32x2;

#define PI_F 3.14159265358979323846f

// ---------------------------------------------------------------------------
// Per-layer weight conversion, one dispatch: wq|wk|wv -> wqkv16 packed, wo -> wo16.
// ---------------------------------------------------------------------------
__global__ __launch_bounds__(256) void cvt_layer(
    const float* __restrict__ wq, const float* __restrict__ wk,
    const float* __restrict__ wv, const float* __restrict__ wo,
    f16* __restrict__ wqkv16, f16* __restrict__ wo16)
{
    const int i = (blockIdx.x * 256 + threadIdx.x) * 4;
    const float* src;
    f16* dst;
    if (i < 3*NWL) {
        dst = wqkv16 + i;
        src = (i < NWL) ? wq + i : (i < 2*NWL) ? wk + (i - NWL) : wv + (i - 2*NWL);
    } else {
        dst = wo16 + (i - 3*NWL);
        src = wo + (i - 3*NWL);
    }
    const float4 v = *(const float4*)src;
    f16 o[4];
    o[0] = (f16)v.x; o[1] = (f16)v.y; o[2] = (f16)v.z; o[3] = (f16)v.w;
    *(ushort4*)dst = *(const ushort4*)o;
}

// ---------------------------------------------------------------------------
// MoE conv: mean over E of conv1d(x, w_e)+b_e == conv1d(x, mean_e w_e)+mean_e b_e
// ---------------------------------------------------------------------------
template<typename IT>
__global__ __launch_bounds__(256) void conv_moe(
    const IT* __restrict__ xin,      // [4096, 2048]
    const float* __restrict__ cw,    // [E, K] layer slice
    const float* __restrict__ cb,    // [E]
    f16* __restrict__ xo)            // [4096, 2048] f16
{
    __shared__ float srow[WD];
    __shared__ float swb[KSZ];
    __shared__ float sbb;
    const int tid = threadIdx.x;
    const size_t row = blockIdx.x;
    if (tid < KSZ) {
        float s = 0.f;
        for (int e = 0; e < ED; ++e) s += cw[e*KSZ + tid];
        swb[tid] = s * (1.f/ED);
    }
    if (tid == 32) {
        float s = 0.f;
        for (int e = 0; e < ED; ++e) s += cb[e];
        sbb = s * (1.f/ED);
    }
    const IT* xr = xin + row*WD;
    if constexpr (sizeof(IT) == 2) {
        const f16x8 v = *(const f16x8*)(xr + tid*8);
        #pragma unroll
        for (int j = 0; j < 8; ++j) srow[tid*8 + j] = (float)v[j];
    } else {
        const float4 v0 = *(const float4*)(xr + tid*8);
        const float4 v1 = *(const float4*)(xr + tid*8 + 4);
        srow[tid*8+0] = v0.x; srow[tid*8+1] = v0.y; srow[tid*8+2] = v0.z; srow[tid*8+3] = v0.w;
        srow[tid*8+4] = v1.x; srow[tid*8+5] = v1.y; srow[tid*8+6] = v1.z; srow[tid*8+7] = v1.w;
    }
    __syncthreads();
    const float bb = sbb;
    float w[32];
    #pragma unroll
    for (int k = 0; k < 32; ++k) {
        const int idx = tid*8 + k - (KSZ/2);
        w[k] = (idx >= 0 && idx < WD) ? srow[idx] : 0.f;
    }
    f16 o[8];
    #pragma unroll
    for (int j = 0; j < 8; ++j) {
        float acc = bb;
        #pragma unroll
        for (int k = 0; k < KSZ; ++k) acc = fmaf(w[j+k], swb[k], acc);
        o[j] = (f16)acc;
    }
    *(f16x8*)(xo + row*WD + tid*8) = *(const f16x8*)o;
}

// ---------------------------------------------------------------------------
// 256x192 pipelined f16 GEMM for QKV (M=4096, K=2048, N=3072):
// grid 16m x 16n = 256 blocks. 512 thr = 8 waves (2M x 4N), per-wave 128x48.
// LDS 112 KiB; XOR-chunk swizzled; 4-barrier schedule with counted waits.
// ---------------------------------------------------------------------------
__global__ __launch_bounds__(512, 2) void gemm192(
    const f16* __restrict__ A,   // [M, K]
    const f16* __restrict__ B,   // [N, K]
    const float* __restrict__ c0, const float* __restrict__ c1, const float* __restrict__ c2,
    f16* __restrict__ out,       // [M, N]
    const int K, const int N)
{
    __shared__ __align__(16) f16 sA[2][2][128*64];
    __shared__ __align__(16) f16 sB[2][3][64*64];

    const int tid  = threadIdx.x;
    const int lane = tid & 63;
    const int wave = tid >> 6;
    const int wr   = wave >> 2;          // 0..1 : A 128-row half
    const int wc   = wave & 3;           // 0..3 : 48-col block
    const int quad = lane >> 4;
    const int r16  = lane & 15;
    const int xrA  = r16 & 7;            // A read-side XOR key

    // 2D XCD chunking: grid 16m x 16n = 256 blocks; XCD owns 4m x 8n (32 blocks)
    const int orig = blockIdx.x;
    const int xcd  = orig & 7;
    const int loc  = orig >> 3;          // 0..31
    const int mt   = (xcd >> 1) * 4 + (loc & 3);
    const int nt   = (xcd & 1) * 8 + (loc >> 2);
    const int m0   = mt * 256;
    const int n0   = nt * 192;

    f32x4 acc[8][3] = {};
    f16x8 bf[3][2];
    f16x8 aX0, aX1, aX2, aX3, aY0, aY1, aY2, aY3, aZ0, aZ1, aZ2, aZ3;

    int soffA[2];
    #pragma unroll
    for (int t = 0; t < 2; ++t) {
        const int s = tid + 512*t;
        const int row = s >> 3;
        soffA[t] = row * K + (((s & 7) ^ (row & 7)) * 8);
    }
    int soffB;
    {
        const int row = tid >> 3;
        soffB = row * K + (((tid & 7) ^ (row & 7)) * 8);
    }

    int bPiece[3], bBase[3], bXor[3];
    #pragma unroll
    for (int j = 0; j < 3; ++j) {
        const int rb = wc*48 + j*16 + r16;
        bPiece[j] = rb >> 6;
        bBase[j]  = (rb & 63) << 3;
        bXor[j]   = rb & 7;
    }

    const f16* Abase[2] = { A + (size_t)m0 * K, A + (size_t)(m0 + 128) * K };
    const f16* Bp[3]    = { B + (size_t)n0 * K, B + (size_t)(n0 + 64) * K,
                            B + (size_t)(n0 + 128) * K };

    #define STAGE_A(BUF, HALF, GOFF)                                              \
      { _Pragma("unroll") for (int t = 0; t < 2; ++t) {                           \
          __builtin_amdgcn_global_load_lds(                                       \
            (const __attribute__((address_space(1))) unsigned int*)(Abase[HALF] + soffA[t] + (GOFF)), \
            (__attribute__((address_space(3))) unsigned int*)&sA[BUF][HALF][(tid + 512*t)*8], \
            16, 0, 0); } }

    #define STAGE_B(BUF, PIECE, GOFF)                                             \
      { __builtin_amdgcn_global_load_lds(                                         \
          (const __attribute__((address_space(1))) unsigned int*)(Bp[PIECE] + soffB + (GOFF)), \
          (__attribute__((address_space(3))) unsigned int*)&sB[BUF][PIECE][tid*8], \
          16, 0, 0); }

    #define LDA(BUF, ROW, C) \
      (*(const f16x8*)&sA[BUF][wr][ (((ROW) << 3) + ((C) ^ xrA)) * 8 ])

    #define LDB(BUF, J, C) \
      (*(const f16x8*)&sB[BUF][bPiece[J]][ (bBase[J] + ((C) ^ bXor[J])) * 8 ])

    #define READ_BF(BUF)                                                          \
      { _Pragma("unroll") for (int j = 0; j < 3; ++j) {                           \
          bf[j][0] = LDB(BUF, j, quad);                                           \
          bf[j][1] = LDB(BUF, j, 4 + quad);                                       \
        } }

    #define READ_A(BUF, Q, D0, D1, D2, D3)                                        \
      D0 = LDA(BUF, (2*(Q))*16   + r16, quad);                                    \
      D1 = LDA(BUF, (2*(Q))*16   + r16, 4 + quad);                                \
      D2 = LDA(BUF, (2*(Q)+1)*16 + r16, quad);                                    \
      D3 = LDA(BUF, (2*(Q)+1)*16 + r16, 4 + quad);

    #define MFMA_Q(Q, D0, D1, D2, D3)                                             \
      __builtin_amdgcn_s_setprio(1);                                              \
      { _Pragma("unroll") for (int jj = 0; jj < 3; ++jj) {                        \
          acc[2*(Q)][jj]   = __builtin_amdgcn_mfma_f32_16x16x32_f16(D0, bf[jj][0], acc[2*(Q)][jj],   0,0,0); \
          acc[2*(Q)+1][jj] = __builtin_amdgcn_mfma_f32_16x16x32_f16(D2, bf[jj][0], acc[2*(Q)+1][jj], 0,0,0); \
        } }                                                                       \
      { _Pragma("unroll") for (int jj = 0; jj < 3; ++jj) {                        \
          acc[2*(Q)][jj]   = __builtin_amdgcn_mfma_f32_16x16x32_f16(D1, bf[jj][1], acc[2*(Q)][jj],   0,0,0); \
          acc[2*(Q)+1][jj] = __builtin_amdgcn_mfma_f32_16x16x32_f16(D3, bf[jj][1], acc[2*(Q)+1][jj], 0,0,0); \
        } }                                                                       \
      __builtin_amdgcn_s_setprio(0);

    #define LGKM(n) asm volatile("s_waitcnt lgkmcnt(" #n ")" ::: "memory");       \
                    __builtin_amdgcn_sched_barrier(0);
    #define VMC(n)  asm volatile("s_waitcnt vmcnt(" #n ")" ::: "memory");
    #define BAR()   __builtin_amdgcn_s_barrier();

    // prologue: B-buf0 (3), A-buf0 (4), B-buf1 (3) -> 10 loads; need oldest 7
    STAGE_B(0, 0, 0); STAGE_B(0, 1, 0); STAGE_B(0, 2, 0);
    STAGE_A(0, 0, 0); STAGE_A(0, 1, 0);
    STAGE_B(1, 0, 64); STAGE_B(1, 1, 64); STAGE_B(1, 2, 64);
    VMC(3)
    BAR()

    const int NIT = K >> 7;   // two K-tiles (BK=64) per iteration
    for (int it = 0; it < NIT; ++it) {
        const bool kl = (it == NIT - 1);
        const int kb1 = (2*it + 1) * 64;
        const int kb2 = kb1 + 64;
        const int kb3 = kb1 + 128;

        // ---------- K-tile 2it : buf0 ----------
        STAGE_A(1, 0, kb1);                                    // P1
        READ_BF(0)
        READ_A(0, 0, aX0, aX1, aX2, aX3)
        LGKM(0)
        MFMA_Q(0, aX0, aX1, aX2, aX3)
        BAR()                                                  // B1
        STAGE_A(1, 1, kb1);                                    // P2
        READ_A(0, 1, aY0, aY1, aY2, aY3)
        READ_A(0, 2, aZ0, aZ1, aZ2, aZ3)
        LGKM(4)
        MFMA_Q(1, aY0, aY1, aY2, aY3)
        if (!kl) { STAGE_B(0, 0, kb2); STAGE_B(0, 1, kb2); }   // P3
        READ_A(0, 3, aX0, aX1, aX2, aX3)
        LGKM(4)
        MFMA_Q(2, aZ0, aZ1, aZ2, aZ3)
        if (!kl) { STAGE_B(0, 2, kb2); }                       // P4
        LGKM(0)
        MFMA_Q(3, aX0, aX1, aX2, aX3)
        if (!kl) { VMC(3) } else { VMC(0) }
        BAR()                                                  // B2

        // ---------- K-tile 2it+1 : buf1 ----------
        if (!kl) STAGE_A(0, 0, kb2);                           // P5
        READ_BF(1)
        READ_A(1, 0, aX0, aX1, aX2, aX3)
        LGKM(0)
        MFMA_Q(0, aX0, aX1, aX2, aX3)
        BAR()                                                  // B3
        if (!kl) STAGE_A(0, 1, kb2);                           // P6
        READ_A(1, 1, aY0, aY1, aY2, aY3)
        READ_A(1, 2, aZ0, aZ1, aZ2, aZ3)
        LGKM(4)
        MFMA_Q(1, aY0, aY1, aY2, aY3)
        if (!kl) { STAGE_B(1, 0, kb3); STAGE_B(1, 1, kb3); }   // P7
        READ_A(1, 3, aX0, aX1, aX2, aX3)
        LGKM(4)
        MFMA_Q(2, aZ0, aZ1, aZ2, aZ3)
        if (!kl) { STAGE_B(1, 2, kb3); }                       // P8
        LGKM(0)
        MFMA_Q(3, aX0, aX1, aX2, aX3)
        if (!kl) { VMC(3) }
        BAR()                                                  // B4
    }

    // epilogue: C/D mapping (16x16x32): col = lane&15, row = quad*4 + r
    #pragma unroll
    for (int j = 0; j < 3; ++j) {
        const int col = n0 + wc*48 + j*16 + r16;
        const float bv = (col < 1024) ? c0[col] : (col < 2048) ? c1[col-1024] : c2[col-2048];
        #pragma unroll
        for (int mi = 0; mi < 8; ++mi) {
            #pragma unroll
            for (int r = 0; r < 4; ++r) {
                const int rowg = m0 + wr*128 + mi*16 + quad*4 + r;
                out[(size_t)rowg*N + col] = (f16)(acc[mi][j][r] + bv);
            }
        }
    }

    #undef STAGE_A
    #undef STAGE_B
    #undef LDA
    #undef LDB
    #undef READ_BF
    #undef READ_A
    #undef MFMA_Q
    #undef LGKM
    #undef VMC
    #undef BAR
}

// ---------------------------------------------------------------------------
// 256x128 pipelined GEMM for the out-projection (M=4096, K=1024, N=2048):
// grid 16m x 16n = 256 blocks (all CUs, 1 round). 4-barrier counted-vmcnt.
// ---------------------------------------------------------------------------
template<typename OT>
__global__ __launch_bounds__(512, 2) void gemmOP(
    const f16* __restrict__ A,   // [M, K]
    const f16* __restrict__ B,   // [N, K]
    const float* __restrict__ c0, const float* __restrict__ c1,
    OT* __restrict__ out,        // [M, N]
    const int K, const int N)
{
    __shared__ __align__(16) f16 sA[2][2][128*64];
    __shared__ __align__(16) f16 sB[2][2][64*64];

    const int tid  = threadIdx.x;
    const int lane = tid & 63;
    const int wave = tid >> 6;
    const int wr   = wave >> 2;          // 0..1 : A 128-row half
    const int wc   = wave & 3;           // 0..3 : 32-col block
    const int quad = lane >> 4;
    const int r16  = lane & 15;
    const int xrA  = r16 & 7;

    const int orig = blockIdx.x;
    const int xcd  = orig & 7;
    const int loc  = orig >> 3;          // 0..31
    const int mt   = (xcd >> 1) * 4 + (loc & 3);
    const int nt   = (xcd & 1) * 8 + (loc >> 2);
    const int m0   = mt * 256;
    const int n0   = nt * 128;

    f32x4 acc[8][2] = {};
    f16x8 bf[2][2];
    f16x8 aX0, aX1, aX2, aX3, aY0, aY1, aY2, aY3, aZ0, aZ1, aZ2, aZ3;

    int soffA[2];
    #pragma unroll
    for (int t = 0; t < 2; ++t) {
        const int s = tid + 512*t;
        const int row = s >> 3;
        soffA[t] = row * K + (((s & 7) ^ (row & 7)) * 8);
    }
    int soffB;
    {
        const int row = tid >> 3;
        soffB = row * K + (((tid & 7) ^ (row & 7)) * 8);
    }

    int bPiece[2], bBase[2], bXor[2];
    #pragma unroll
    for (int j = 0; j < 2; ++j) {
        const int rb = wc*32 + j*16 + r16;
        bPiece[j] = rb >> 6;
        bBase[j]  = (rb & 63) << 3;
        bXor[j]   = rb & 7;
    }

    const f16* Abase[2] = { A + (size_t)m0 * K, A + (size_t)(m0 + 128) * K };
    const f16* Bp[2]    = { B + (size_t)n0 * K, B + (size_t)(n0 + 64) * K };

    #define STAGE_A(BUF, HALF, GOFF)                                              \
      { _Pragma("unroll") for (int t = 0; t < 2; ++t) {                           \
          __builtin_amdgcn_global_load_lds(                                       \
            (const __attribute__((address_space(1))) unsigned int*)(Abase[HALF] + soffA[t] + (GOFF)), \
            (__attribute__((address_space(3))) unsigned int*)&sA[BUF][HALF][(tid + 512*t)*8], \
            16, 0, 0); } }

    #define STAGE_B(BUF, PIECE, GOFF)                                             \
      { __builtin_amdgcn_global_load_lds(                                         \
          (const __attribute__((address_space(1))) unsigned int*)(Bp[PIECE] + soffB + (GOFF)), \
          (__attribute__((address_space(3))) unsigned int*)&sB[BUF][PIECE][tid*8], \
          16, 0, 0); }

    #define LDA(BUF, ROW, C) \
      (*(const f16x8*)&sA[BUF][wr][ (((ROW) << 3) + ((C) ^ xrA)) * 8 ])

    #define LDB(BUF, J, C) \
      (*(const f16x8*)&sB[BUF][bPiece[J]][ (bBase[J] + ((C) ^ bXor[J])) * 8 ])

    #define READ_BF(BUF)                                                          \
      { _Pragma("unroll") for (int j = 0; j < 2; ++j) {                           \
          bf[j][0] = LDB(BUF, j, quad);                                           \
          bf[j][1] = LDB(BUF, j, 4 + quad);                                       \
        } }

    #define READ_A(BUF, Q, D0, D1, D2, D3)                                        \
      D0 = LDA(BUF, (2*(Q))*16   + r16, quad);                                    \
      D1 = LDA(BUF, (2*(Q))*16   + r16, 4 + quad);                                \
      D2 = LDA(BUF, (2*(Q)+1)*16 + r16, quad);                                    \
      D3 = LDA(BUF, (2*(Q)+1)*16 + r16, 4 + quad);

    #define MFMA_Q(Q, D0, D1, D2, D3)                                             \
      __builtin_amdgcn_s_setprio(1);                                              \
      { _Pragma("unroll") for (int jj = 0; jj < 2; ++jj) {                        \
          acc[2*(Q)][jj]   = __builtin_amdgcn_mfma_f32_16x16x32_f16(D0, bf[jj][0], acc[2*(Q)][jj],   0,0,0); \
          acc[2*(Q)+1][jj] = __builtin_amdgcn_mfma_f32_16x16x32_f16(D2, bf[jj][0], acc[2*(Q)+1][jj], 0,0,0); \
        } }                                                                       \
      { _Pragma("unroll") for (int jj = 0; jj < 2; ++jj) {                        \
          acc[2*(Q)][jj]   = __builtin_amdgcn_mfma_f32_16x16x32_f16(D1, bf[jj][1], acc[2*(Q)][jj],   0,0,0); \
          acc[2*(Q)+1][jj] = __builtin_amdgcn_mfma_f32_16x16x32_f16(D3, bf[jj][1], acc[2*(Q)+1][jj], 0,0,0); \
        } }                                                                       \
      __builtin_amdgcn_s_setprio(0);

    #define LGKM(n) asm volatile("s_waitcnt lgkmcnt(" #n ")" ::: "memory");       \
                    __builtin_amdgcn_sched_barrier(0);
    #define VMC(n)  asm volatile("s_waitcnt vmcnt(" #n ")" ::: "memory");
    #define BAR()   __builtin_amdgcn_s_barrier();

    STAGE_B(0, 0, 0); STAGE_B(0, 1, 0);
    STAGE_A(0, 0, 0); STAGE_A(0, 1, 0);
    STAGE_B(1, 0, 64); STAGE_B(1, 1, 64);
    VMC(2)
    BAR()

    const int NIT = K >> 7;   // two K-tiles (BK=64) per iteration
    for (int it = 0; it < NIT; ++it) {
        const bool kl = (it == NIT - 1);
        const int kb1 = (2*it + 1) * 64;
        const int kb2 = kb1 + 64;
        const int kb3 = kb1 + 128;

        STAGE_A(1, 0, kb1);                                    // P1
        READ_BF(0)
        READ_A(0, 0, aX0, aX1, aX2, aX3)
        LGKM(0)
        MFMA_Q(0, aX0, aX1, aX2, aX3)
        BAR()                                                  // B1
        STAGE_A(1, 1, kb1);                                    // P2
        READ_A(0, 1, aY0, aY1, aY2, aY3)
        READ_A(0, 2, aZ0, aZ1, aZ2, aZ3)
        LGKM(4)
        MFMA_Q(1, aY0, aY1, aY2, aY3)
        if (!kl) { STAGE_B(0, 0, kb2); }                       // P3
        READ_A(0, 3, aX0, aX1, aX2, aX3)
        LGKM(4)
        MFMA_Q(2, aZ0, aZ1, aZ2, aZ3)
        if (!kl) { STAGE_B(0, 1, kb2); }                       // P4
        LGKM(0)
        MFMA_Q(3, aX0, aX1, aX2, aX3)
        if (!kl) { VMC(2) } else { VMC(0) }
        BAR()                                                  // B2

        if (!kl) STAGE_A(0, 0, kb2);                           // P5
        READ_BF(1)
        READ_A(1, 0, aX0, aX1, aX2, aX3)
        LGKM(0)
        MFMA_Q(0, aX0, aX1, aX2, aX3)
        BAR()                                                  // B3
        if (!kl) STAGE_A(0, 1, kb2);                           // P6
        READ_A(1, 1, aY0, aY1, aY2, aY3)
        READ_A(1, 2, aZ0, aZ1, aZ2, aZ3)
        LGKM(4)
        MFMA_Q(1, aY0, aY1, aY2, aY3)
        if (!kl) { STAGE_B(1, 0, kb3); }                       // P7
        READ_A(1, 3, aX0, aX1, aX2, aX3)
        LGKM(4)
        MFMA_Q(2, aZ0, aZ1, aZ2, aZ3)
        if (!kl) { STAGE_B(1, 1, kb3); }                       // P8
        LGKM(0)
        MFMA_Q(3, aX0, aX1, aX2, aX3)
        if (!kl) { VMC(2) }
        BAR()                                                  // B4
    }

    #pragma unroll
    for (int j = 0; j < 2; ++j) {
        const int col = n0 + wc*32 + j*16 + r16;
        const float bv = (col < 1024) ? c0[col] : c1[col-1024];
        #pragma unroll
        for (int mi = 0; mi < 8; ++mi) {
            #pragma unroll
            for (int r = 0; r < 4; ++r) {
                const int rowg = m0 + wr*128 + mi*16 + quad*4 + r;
                out[(size_t)rowg*N + col] = (OT)(acc[mi][j][r] + bv);
            }
        }
    }

    #undef STAGE_A
    #undef STAGE_B
    #undef LDA
    #undef LDB
    #undef READ_BF
    #undef READ_A
    #undef MFMA_Q
    #undef LGKM
    #undef VMC
    #undef BAR
}

// ---------------------------------------------------------------------------
// Wave-local FFT attention: one WAVE per row-pair, ZERO block barriers.
// 1024-pt FFT decomposed as 16x64 (Cooley-Tukey):
//   n = 64*j + l  (l = lane, j = register index 0..15)
//   X[k1 + 16*k2] = FFT64_over_l( W1024^(l*k1) * DFT16_over_j(x)[k1] )[k2]
// Step A: 16-pt DFT in registers (radix-4 x radix-4, literal twiddles).
// Step B: W1024^(l*k1) from 4 hoisted sincos (binary-power products).
// Step C: 16 channels x 64-pt Stockham radix-4 across lanes, 3 stages,
//   LDS exchange with stride-65 rows + i^((i>>4)<<2) XOR swizzle
//   (verified uniform 4-deep b64 bank spread on all stage reads/writes).
// All sync is wave-synchronous s_waitcnt lgkmcnt(0) (no __syncthreads).
// LDS: 4 waves x 2 buffers x 16x65 f32x2 = 65 KiB -> 2 blocks/CU.
// ---------------------------------------------------------------------------
__device__ __forceinline__ f32x2 cmul2(const f32x2 a, const float wc, const float ws) {
    f32x2 r; r.x = a.x*wc - a.y*ws; r.y = a.y*wc + a.x*ws; return r;
}

#define IZ(c,i) ((c)*65 + ((i) ^ ((((i) >> 4) & 3) << 2)))
#define WSYNC() { asm volatile("s_waitcnt lgkmcnt(0)" ::: "memory"); \
                  __builtin_amdgcn_sched_barrier(0); }

__global__ __launch_bounds__(256) void fft_attn_wave(
    const f16* __restrict__ qkv, f16* __restrict__ outg)
{
    __shared__ f32x2 ZZ[4][2][16*65];      // 66,560 B
    const int tid = threadIdx.x;
    const int w   = tid >> 6;
    const int l   = tid & 63;
    const int t   = l & 15;                // slot within a 64-pt FFT
    const int cg  = l >> 4;                // channel-group base (0..3)
    f32x2* Z1 = &ZZ[w][0][0];
    f32x2* Z2 = &ZZ[w][1][0];
    f16*   sc = (f16*)Z1;                  // 4 KiB staging scratch (aliases Z1)

    const size_t rp = (size_t)blockIdx.x*4 + w;
    const f16* r1 = qkv + (2*rp)*QKVN;     // q1 | k1 | v1
    const f16* r2 = r1 + QKVN;             // q2 | k2 | v2

    // ---- hoisted twiddles ----
    // W1024^(l*k), k=0..15, from 4 sincos + binary-power complex products
    float bwc[16], bws[16];
    {
        const float th = -2.f*PI_F*(float)l*(1.f/1024.f);
        bwc[0]=1.f; bws[0]=0.f;
        __sincosf(th,     &bws[1], &bwc[1]);
        __sincosf(2.f*th, &bws[2], &bwc[2]);
        __sincosf(4.f*th, &bws[4], &bwc[4]);
        __sincosf(8.f*th, &bws[8], &bwc[8]);
        bwc[3]=bwc[1]*bwc[2]-bws[1]*bws[2]; bws[3]=bws[1]*bwc[2]+bwc[1]*bws[2];
        bwc[5]=bwc[1]*bwc[4]-bws[1]*bws[4]; bws[5]=bws[1]*bwc[4]+bwc[1]*bws[4];
        bwc[6]=bwc[2]*bwc[4]-bws[2]*bws[4]; bws[6]=bws[2]*bwc[4]+bwc[2]*bws[4];
        bwc[7]=bwc[3]*bwc[4]-bws[3]*bws[4]; bws[7]=bws[3]*bwc[4]+bwc[3]*bws[4];
        #pragma unroll
        for (int k = 9; k < 16; ++k) {
            bwc[k]=bwc[k-8]*bwc[8]-bws[k-8]*bws[8];
            bws[k]=bws[k-8]*bwc[8]+bwc[k-8]*bws[8];
        }
    }
    // stage-C lane twiddles: st0 angle -2pi*t/64, st1 angle -2pi*(t>>2)/16
    float c0s, c0c, c1s, c1c;
    __sincosf(-2.f*PI_F*(float)t*(1.f/64.f), &c0s, &c0c);
    __sincosf(-2.f*PI_F*(float)(t>>2)*(1.f/16.f), &c1s, &c1c);

    // W16^k literals (cos, -sin of 2*pi*k/16); indices used: 0..4,6,9
    const float W16C[10] = {1.f, 0.92387953f, 0.70710678f, 0.38268343f, 0.f,
                            0.f, -0.70710678f, 0.f, 0.f, -0.92387953f};
    const float W16S[10] = {0.f, -0.38268343f, -0.70710678f, -0.92387953f, -1.f,
                            0.f, -0.70710678f, 0.f, 0.f, 0.38268343f};

    f32x2 v[16], V1[16], V2[16];

    // ---- FFT core: v (time, n = l+64j) -> spectrum in Z2 (natural order) ----
    auto run_fft = [&]() {
        // step A: 16-pt DFT over j
        f32x2 C[4][4];
        #pragma unroll
        for (int jj = 0; jj < 4; ++jj) {
            const f32x2 a = v[jj], b = v[jj+4], c = v[jj+8], d = v[jj+12];
            f32x2 t0, t1, t2, t3;
            t0.x=a.x+c.x; t0.y=a.y+c.y; t1.x=a.x-c.x; t1.y=a.y-c.y;
            t2.x=b.x+d.x; t2.y=b.y+d.y; t3.x=b.x-d.x; t3.y=b.y-d.y;
            f32x2 B0, B1, B2, B3;
            B0.x=t0.x+t2.x; B0.y=t0.y+t2.y;
            B1.x=t1.x+t3.y; B1.y=t1.y-t3.x;      // t1 - i*t3
            B2.x=t0.x-t2.x; B2.y=t0.y-t2.y;
            B3.x=t1.x-t3.y; B3.y=t1.y+t3.x;      // t1 + i*t3
            C[0][jj] = B0;
            C[1][jj] = cmul2(B1, W16C[jj],   W16S[jj]);
            C[2][jj] = cmul2(B2, W16C[2*jj], W16S[2*jj]);
            C[3][jj] = cmul2(B3, W16C[3*jj], W16S[3*jj]);
        }
        f32x2 g[16];
        #pragma unroll
        for (int q = 0; q < 4; ++q) {
            const f32x2 c0 = C[q][0], c1 = C[q][1], c2 = C[q][2], c3 = C[q][3];
            f32x2 e0, o0, e1, o1;
            e0.x=c0.x+c2.x; e0.y=c0.y+c2.y; o0.x=c1.x+c3.x; o0.y=c1.y+c3.y;
            e1.x=c0.x-c2.x; e1.y=c0.y-c2.y; o1.x=c1.x-c3.x; o1.y=c1.y-c3.y;
            g[q].x    = e0.x+o0.x; g[q].y    = e0.y+o0.y;
            g[q+4].x  = e1.x+o1.y; g[q+4].y  = e1.y-o1.x;   // e1 - i*o1
            g[q+8].x  = e0.x-o0.x; g[q+8].y  = e0.y-o0.y;
            g[q+12].x = e1.x-o1.y; g[q+12].y = e1.y+o1.x;   // e1 + i*o1
        }
        // step B: twiddle, write to Z1 (k1-major)
        WSYNC()   // retire any pending reads of the Z1/sc region before overwrite
        #pragma unroll
        for (int k = 0; k < 16; ++k)
            Z1[IZ(k, l)] = cmul2(g[k], bwc[k], bws[k]);
        WSYNC()
        // step C: 3 Stockham radix-4 stages across lanes, 4 channel passes each
        // st0: Z1 -> Z2, s=1, p=t, q=0, twiddle (c0c,c0s)
        #pragma unroll
        for (int pass = 0; pass < 4; ++pass) {
            const int c = cg + 4*pass;
            const f32x2 a = Z1[IZ(c, t)],     b = Z1[IZ(c, t+16)];
            const f32x2 cc = Z1[IZ(c, t+32)], d = Z1[IZ(c, t+48)];
            const float apcx=a.x+cc.x, apcy=a.y+cc.y, amcx=a.x-cc.x, amcy=a.y-cc.y;
            const float bpdx=b.x+d.x,  bpdy=b.y+d.y,  bmdx=b.x-d.x,  bmdy=b.y-d.y;
            f32x2 y0; y0.x=apcx+bpdx; y0.y=apcy+bpdy;
            const float t1x=amcx+bmdy, t1y=amcy-bmdx;
            const float t2x=apcx-bpdx, t2y=apcy-bpdy;
            const float t3x=amcx-bmdy, t3y=amcy+bmdx;
            const float w2x=c0c*c0c-c0s*c0s, w2y=2.f*c0c*c0s;
            const float w3x=w2x*c0c-w2y*c0s, w3y=w2x*c0s+w2y*c0c;
            f32x2 y1; y1.x=c0c*t1x-c0s*t1y; y1.y=c0c*t1y+c0s*t1x;
            f32x2 y2; y2.x=w2x*t2x-w2y*t2y; y2.y=w2x*t2y+w2y*t2x;
            f32x2 y3; y3.x=w3x*t3x-w3y*t3y; y3.y=w3x*t3y+w3y*t3x;
            const int i0 = 4*t;
            Z2[IZ(c, i0)]   = y0; Z2[IZ(c, i0+1)] = y1;
            Z2[IZ(c, i0+2)] = y2; Z2[IZ(c, i0+3)] = y3;
        }
        WSYNC()
        // st1: Z2 -> Z1, s=4, p=t>>2, q=t&3, twiddle (c1c,c1s)
        #pragma unroll
        for (int pass = 0; pass < 4; ++pass) {
            const int c = cg + 4*pass;
            const f32x2 a = Z2[IZ(c, t)],     b = Z2[IZ(c, t+16)];
            const f32x2 cc = Z2[IZ(c, t+32)], d = Z2[IZ(c, t+48)];
            const float apcx=a.x+cc.x, apcy=a.y+cc.y, amcx=a.x-cc.x, amcy=a.y-cc.y;
            const float bpdx=b.x+d.x,  bpdy=b.y+d.y,  bmdx=b.x-d.x,  bmdy=b.y-d.y;
            f32x2 y0; y0.x=apcx+bpdx; y0.y=apcy+bpdy;
            const float t1x=amcx+bmdy, t1y=amcy-bmdx;
            const float t2x=apcx-bpdx, t2y=apcy-bpdy;
            const float t3x=amcx-bmdy, t3y=amcy+bmdx;
            const float w2x=c1c*c1c-c1s*c1s, w2y=2.f*c1c*c1s;
            const float w3x=w2x*c1c-w2y*c1s, w3y=w2x*c1s+w2y*c1c;
            f32x2 y1; y1.x=c1c*t1x-c1s*t1y; y1.y=c1c*t1y+c1s*t1x;
            f32x2 y2; y2.x=w2x*t2x-w2y*t2y; y2.y=w2x*t2y+w2y*t2x;
            f32x2 y3; y3.x=w3x*t3x-w3y*t3y; y3.y=w3x*t3y+w3y*t3x;
            const int i0 = (t & 3) + 16*(t >> 2);
            Z1[IZ(c, i0)]    = y0; Z1[IZ(c, i0+4)]  = y1;
            Z1[IZ(c, i0+8)]  = y2; Z1[IZ(c, i0+12)] = y3;
        }
        WSYNC()
        // st2: Z1 -> Z2, s=16, p=0 (twiddle = 1), q=t
        #pragma unroll
        for (int pass = 0; pass < 4; ++pass) {
            const int c = cg + 4*pass;
            const f32x2 a = Z1[IZ(c, t)],     b = Z1[IZ(c, t+16)];
            const f32x2 cc = Z1[IZ(c, t+32)], d = Z1[IZ(c, t+48)];
            const float apcx=a.x+cc.x, apcy=a.y+cc.y, amcx=a.x-cc.x, amcy=a.y-cc.y;
            const float bpdx=b.x+d.x,  bpdy=b.y+d.y,  bmdx=b.x-d.x,  bmdy=b.y-d.y;
            f32x2 y0; y0.x=apcx+bpdx; y0.y=apcy+bpdy;
            f32x2 y1; y1.x=amcx+bmdy; y1.y=amcy-bmdx;
            f32x2 y2; y2.x=apcx-bpdx; y2.y=apcy-bpdy;
            f32x2 y3; y3.x=amcx-bmdy; y3.y=amcy+bmdx;
            Z2[IZ(c, t)]    = y0; Z2[IZ(c, t+16)] = y1;
            Z2[IZ(c, t+32)] = y2; Z2[IZ(c, t+48)] = y3;
        }
        WSYNC()
    };

    // ---- stage helper: two 1024-f16 segments -> sc[0..1023], sc[1024..2047] ----
    auto stage2 = [&](const f16* a, const f16* b) {
        const f16x8 a0 = *(const f16x8*)(a + l*8);
        const f16x8 a1 = *(const f16x8*)(a + (l+64)*8);
        const f16x8 b0 = *(const f16x8*)(b + l*8);
        const f16x8 b1 = *(const f16x8*)(b + (l+64)*8);
        WSYNC()   // retire prior reads of the sc/Z1 region before overwrite
        *(f16x8*)&sc[l*8]          = a0;
        *(f16x8*)&sc[(l+64)*8]     = a1;
        *(f16x8*)&sc[1024+l*8]     = b0;
        *(f16x8*)&sc[1024+(l+64)*8]= b1;
        WSYNC()
    };

    // ================= FFT 1: v1 + i*v2 =================
    stage2(r1 + 2048, r2 + 2048);
    #pragma unroll
    for (int j = 0; j < 16; ++j) {
        v[j].x = (float)sc[l + 64*j];
        v[j].y = (float)sc[1024 + l + 64*j];
    }
    run_fft();
    #pragma unroll
    for (int j = 0; j < 16; ++j) {
        const int f = l + 64*j;
        const int gg = (PD - f) & (PD-1);
        const f32x2 z1 = Z2[IZ(f & 15, f >> 4)];
        const f32x2 z2 = Z2[IZ(gg & 15, gg >> 4)];
        V1[j].x = 0.5f*(z1.x + z2.x); V1[j].y = 0.5f*(z1.y - z2.y);
        V2[j].x = 0.5f*(z1.y + z2.y); V2[j].y = 0.5f*(z2.x - z1.x);
    }

    // ================= FFT 2: q1 + i*k1 ; S1 -> V1 =================
    {
        const f16x8 a0 = *(const f16x8*)(r1 + l*8);
        const f16x8 a1 = *(const f16x8*)(r1 + (l+64)*8);
        const f16x8 a2 = *(const f16x8*)(r1 + (l+128)*8);
        const f16x8 a3 = *(const f16x8*)(r1 + (l+192)*8);
        WSYNC()
        *(f16x8*)&sc[l*8]        = a0;
        *(f16x8*)&sc[(l+64)*8]   = a1;
        *(f16x8*)&sc[(l+128)*8]  = a2;
        *(f16x8*)&sc[(l+192)*8]  = a3;
        WSYNC()
    }
    #pragma unroll
    for (int j = 0; j < 16; ++j) {
        v[j].x = (float)sc[l + 64*j];
        v[j].y = (float)sc[1024 + l + 64*j];
    }
    run_fft();
    #pragma unroll
    for (int j = 0; j < 16; ++j) {
        const int f = l + 64*j;
        const int gg = (PD - f) & (PD-1);
        const f32x2 z1 = Z2[IZ(f & 15, f >> 4)];
        const f32x2 z2 = Z2[IZ(gg & 15, gg >> 4)];
        const float Qr = 0.5f*(z1.x + z2.x), Qi = 0.5f*(z1.y - z2.y);
        const float Kr = 0.5f*(z1.y + z2.y), Ki = 0.5f*(z2.x - z1.x);
        const float Pr = (Kr*Qr + Ki*Qi) * (1.f/32.f);
        const float Pi = (Ki*Qr - Kr*Qi) * (1.f/32.f);
        const float sx = Pr*V1[j].x - Pi*V1[j].y;
        const float sy = -(Pr*V1[j].y + Pi*V1[j].x);
        V1[j].x = sx; V1[j].y = sy;
    }

    // ================= FFT 3: q2 + i*k2 ; S2 -> V2 =================
    {
        const f16x8 a0 = *(const f16x8*)(r2 + l*8);
        const f16x8 a1 = *(const f16x8*)(r2 + (l+64)*8);
        const f16x8 a2 = *(const f16x8*)(r2 + (l+128)*8);
        const f16x8 a3 = *(const f16x8*)(r2 + (l+192)*8);
        WSYNC()
        *(f16x8*)&sc[l*8]        = a0;
        *(f16x8*)&sc[(l+64)*8]   = a1;
        *(f16x8*)&sc[(l+128)*8]  = a2;
        *(f16x8*)&sc[(l+192)*8]  = a3;
        WSYNC()
    }
    #pragma unroll
    for (int j = 0; j < 16; ++j) {
        v[j].x = (float)sc[l + 64*j];
        v[j].y = (float)sc[1024 + l + 64*j];
    }
    run_fft();
    #pragma unroll
    for (int j = 0; j < 16; ++j) {
        const int f = l + 64*j;
        const int gg = (PD - f) & (PD-1);
        const f32x2 z1 = Z2[IZ(f & 15, f >> 4)];
        const f32x2 z2 = Z2[IZ(gg & 15, gg >> 4)];
        const float Qr = 0.5f*(z1.x + z2.x), Qi = 0.5f*(z1.y - z2.y);
        const float Kr = 0.5f*(z1.y + z2.y), Ki = 0.5f*(z2.x - z1.x);
        const float Pr = (Kr*Qr + Ki*Qi) * (1.f/32.f);
        const float Pi = (Ki*Qr - Kr*Qi) * (1.f/32.f);
        const float sx = Pr*V2[j].x - Pi*V2[j].y;
        const float sy = -(Pr*V2[j].y + Pi*V2[j].x);
        V2[j].x = sx; V2[j].y = sy;
    }

    // ================= FFT 4: packed inverse S1 + i*S2 =================
    #pragma unroll
    for (int j = 0; j < 16; ++j) {
        v[j].x = V1[j].x - V2[j].y;
        v[j].y = V1[j].y + V2[j].x;
    }
    run_fft();

    // ---- output: bounce through sc for vectorized global stores ----
    #pragma unroll
    for (int j = 0; j < 16; ++j) {
        const int n = l + 64*j;
        const f32x2 z = Z2[IZ(n & 15, n >> 4)];
        sc[n]        = (f16)(z.x * (1.f/1024.f));
        sc[1024 + n] = (f16)(z.y * (1.f/1024.f));
    }
    WSYNC()
    f16* o1 = outg + (2*rp)*PD;
    f16* o2 = o1 + PD;
    *(f16x8*)(o1 + l*8)      = *(const f16x8*)&sc[l*8];
    *(f16x8*)(o1 + (l+64)*8) = *(const f16x8*)&sc[(l+64)*8];
    *(f16x8*)(o2 + l*8)      = *(const f16x8*)&sc[1024 + l*8];
    *(f16x8*)(o2 + (l+64)*8) = *(const f16x8*)&sc[1024 + (l+64)*8];
}

// ---------------------------------------------------------------------------
extern "C" void kernel_launch(void* const* d_in, const int* in_sizes, int n_in,
                              void* d_out, int out_size, void* d_ws, size_t ws_size,
                              hipStream_t stream)
{
    const float* x      = (const float*)d_in[0];
    const float* conv_w = (const float*)d_in[1];   // [L,E,1,K]
    const float* conv_b = (const float*)d_in[2];   // [L,E]
    const float* wq     = (const float*)d_in[3];   // [L,P,W]
    const float* bq     = (const float*)d_in[4];   // [L,P]
    const float* wk     = (const float*)d_in[5];
    const float* bk     = (const float*)d_in[6];
    const float* wv     = (const float*)d_in[7];
    const float* bv     = (const float*)d_in[8];
    const float* wo     = (const float*)d_in[9];   // [L,W,P]
    const float* bo     = (const float*)d_in[10];  // [L,W]

    // workspace layout, per-layer weight slots reused:
    //   0M..12M : wqkv16 f16 [3072, 2048]
    //  12M..16M : wo16   f16 [2048, 1024]
    //  16M..40M : qkvbuf f16 [4096, 3072]
    //  40M..56M : xc16   f16 [4096, 2048]  (first 8 MiB aliased wvr16 [4096,1024])
    //  56M..72M : xmid   f16 [4096, 2048]
    char* ws = (char*)d_ws;
    const size_t MB = 1024*1024;
    f16*   wqkv16 = (f16*)(ws);
    f16*   wo16   = (f16*)(ws + 12*MB);
    f16*   qkvbuf = (f16*)(ws + 16*MB);
    f16*   xc16   = (f16*)(ws + 40*MB);
    f16*   xmid   = (f16*)(ws + 56*MB);
    f16*   wvr16  = xc16;   // alias: xc dead once the QKV GEMM completes

    for (int l = 0; l < LN; ++l) {
        cvt_layer<<<dim3(4*NWL/4/256), dim3(256), 0, stream>>>(
            wq + (size_t)l*NWL, wk + (size_t)l*NWL, wv + (size_t)l*NWL, wo + (size_t)l*NWL,
            wqkv16, wo16);

        if (l == 0)
            conv_moe<float><<<dim3(MROWS), dim3(256), 0, stream>>>(
                x, conv_w, conv_b, xc16);
        else
            conv_moe<f16><<<dim3(MROWS), dim3(256), 0, stream>>>(
                xmid, conv_w + (size_t)l*ED*KSZ, conv_b + (size_t)l*ED, xc16);

        // qkv = xc @ wqkv^T + [bq|bk|bv]   (M=4096, K=2048, N=3072), f16 out
        gemm192<<<dim3((MROWS/256)*(QKVN/192)), dim3(512), 0, stream>>>(
            xc16, wqkv16,
            bq + (size_t)l*PD, bk + (size_t)l*PD, bv + (size_t)l*PD,
            qkvbuf, WD, QKVN);

        // wave-local FFT attention: 8 rows/block, 512 blocks, zero barriers
        fft_attn_wave<<<dim3(MROWS/8), dim3(256), 0, stream>>>(qkvbuf, wvr16);

        // xnext = wvr @ wo^T + bo  (M=4096, K=1024, N=2048)
        if (l == LN-1)
            gemmOP<float><<<dim3((MROWS/256)*(WD/128)), dim3(512), 0, stream>>>(
                wvr16, wo16,
                bo + (size_t)l*WD, bo + (size_t)l*WD + PD,
                (float*)d_out, PD, WD);
        else
            gemmOP<f16><<<dim3((MROWS/256)*(WD/128)), dim3(512), 0, stream>>>(
                wvr16, wo16,
                bo + (size_t)l*WD, bo + (size_t)l*WD + PD,
                xmid, PD, WD);
    }
}